// Round 1
// baseline (437.446 us; speedup 1.0000x reference)
//
#include <hip/hip_runtime.h>
#include <hip/hip_fp16.h>
#include <hip/hip_cooperative_groups.h>
#include <math.h>

namespace cg = cooperative_groups;

#define FIN   128
#define NHH   4
#define NNODE 50000
#define NEDGE 800000
#define NTILE 782       // ceil(50000/64)
#define XROW  136       // 128 k + 8 pad (halves)
#define DCAP  64        // per-target slot capacity (deg~Poisson(16); P(>64)~2e-18)
#define SCHUNK 2048     // edges per scatter chunk
#define NCHUNK 391      // ceil(NEDGE/SCHUNK)
#define NSCAT  (NCHUNK * 8)   // 3128 scatter units (chunk x 8 XCD-ranges)
#define TRANGE 6250     // NNODE / 8 targets per XCD-range
#define ZBLK   49       // cursor-zero units
#define NU1    4704     // 196 groups x 24 (16 scatter + 8 proj); guards trim overshoot
#define NAGG   12504    // 8 ranges x ceil(6250/4) aggregate units

typedef _Float16 half8   __attribute__((ext_vector_type(8)));
typedef float    floatx4 __attribute__((ext_vector_type(4)));

__device__ __forceinline__ float lrelu(float x) { return x > 0.f ? x : 0.2f * x; }

// ---------------------------------------------------------------------------
// Unit bodies (shared by the fused cooperative kernel and the fallback path)
// ---------------------------------------------------------------------------

// Wt/Ws -> f16 fragment-tiled conversion; unit b in [0,16)
__device__ __forceinline__
void prep_w_unit(int b, const float* __restrict__ Wt, const float* __restrict__ Ws,
                 __half* __restrict__ wf16)
{
    const float* W = (b >> 3) ? Ws : Wt;
    __half* o = wf16 + (size_t)(b >> 3) * 16384;
    const int fr = (b & 7) * 256 + threadIdx.x;   // 0..2047
    const int l = fr & 63;
    const int s = (fr >> 6) & 3;
    const int t = (fr >> 8) & 1;
    const int w = fr >> 9;
    const int c  = w * 32 + t * 16 + (l & 15);
    const int k0 = s * 32 + (l >> 4) * 8;
    __half tmp[8];
    #pragma unroll
    for (int j = 0; j < 8; ++j)
        tmp[j] = __float2half_rn(W[(k0 + j) * 128 + c]);
    *(uint4*)(o + (size_t)fr * 8) = *(uint4*)tmp;
}

// zero the per-target cursor; unit zb in [0,ZBLK)
__device__ __forceinline__
void zero_unit(int zb, int* __restrict__ cursor)
{
    const int i = (zb * 256 + threadIdx.x) * 4;
    if (i < NNODE) {
        if (i + 4 <= NNODE) *(int4*)(cursor + i) = make_int4(0, 0, 0, 0);
        else for (int k = i; k < NNODE; ++k) cursor[k] = 0;
    }
}

// XCD-partitioned slot scatter; unit s in [0,NSCAT): chunk s>>3, range s&7.
// Requires executing block's (blockIdx&7) == (s&7) for the L2-ownership
// heuristic (perf only; correctness independent of the mapping).
__device__ __forceinline__
void scatter_unit(int s, const int* __restrict__ ei, int* __restrict__ cursor,
                  int* __restrict__ slots)
{
    const int base = (s >> 3) * SCHUNK;
    const unsigned lo = (unsigned)((s & 7) * TRANGE);
    #pragma unroll
    for (int k = 0; k < 8; ++k) {
        const int e = base + k * 256 + threadIdx.x;
        if (e < NEDGE) {
            const int ti = ei[NEDGE + e];
            const int si = ei[e];                       // coalesced; filtered below
            if ((unsigned)(ti - lo) < (unsigned)TRANGE) {
                const int p = atomicAdd(cursor + ti, 1);
                if (p < DCAP) slots[ti * DCAP + p] = si;
            }
        }
    }
}

// MFMA f16 projection body: block-unit = 64 nodes, wave w = head w.
// D layout: channel = (lane&15) + 16*t within head; node = m4*16+(lane>>4)*4+reg.
// STORE: src_proj packed f16x2: dword w*16+n holds channels (32w+n, 32w+16+n).
template<int STORE>
__device__ __forceinline__
void proj_body(int bb, const float* __restrict__ X, const __half* __restrict__ Wf,
               const float* __restrict__ a, unsigned int* __restrict__ proj_pk,
               float* __restrict__ scores, __half* xl)
{
    __syncthreads();   // guard xl against the block's previous proj unit (grid-stride reuse)
    const int tid  = threadIdx.x;
    const int lane = tid & 63;
    const int w    = __builtin_amdgcn_readfirstlane(tid >> 6);
    const int n0   = bb * 64;

    {
        const int row = tid >> 2;
        const float4* X4 = (const float4*)X;
        __half2* dst = (__half2*)(xl + row * XROW + (tid & 3) * 32);
        #pragma unroll
        for (int q = 0; q < 8; ++q) {
            float4 v = make_float4(0.f, 0.f, 0.f, 0.f);
            if (n0 + row < NNODE) v = X4[(size_t)(n0 + row) * 32 + (tid & 3) * 8 + q];
            dst[q * 2 + 0] = __halves2half2(__float2half_rn(v.x), __float2half_rn(v.y));
            dst[q * 2 + 1] = __halves2half2(__float2half_rn(v.z), __float2half_rn(v.w));
        }
    }
    __syncthreads();

    half8 bf[2][4];
    {
        const uint4* Bp = (const uint4*)Wf;
        #pragma unroll
        for (int t = 0; t < 2; ++t)
            #pragma unroll
            for (int s = 0; s < 4; ++s) {
                uint4 u = Bp[((size_t)((w * 2 + t) * 4 + s)) * 64 + lane];
                bf[t][s] = *(half8*)&u;
            }
    }

    floatx4 acc[4][2];
    #pragma unroll
    for (int m4 = 0; m4 < 4; ++m4) { acc[m4][0] = (floatx4)0.f; acc[m4][1] = (floatx4)0.f; }

    #pragma unroll
    for (int m4 = 0; m4 < 4; ++m4) {
        #pragma unroll
        for (int s = 0; s < 4; ++s) {
            const half8 af = *(const half8*)(xl + (m4 * 16 + (lane & 15)) * XROW
                                                + s * 32 + (lane >> 4) * 8);
            acc[m4][0] = __builtin_amdgcn_mfma_f32_16x16x32_f16(af, bf[0][s], acc[m4][0], 0, 0, 0);
            acc[m4][1] = __builtin_amdgcn_mfma_f32_16x16x32_f16(af, bf[1][s], acc[m4][1], 0, 0, 0);
        }
    }

    const float a0 = a[w * 32 + (lane & 15)];
    const float a1 = a[w * 32 + 16 + (lane & 15)];
    #pragma unroll
    for (int m4 = 0; m4 < 4; ++m4) {
        #pragma unroll
        for (int reg = 0; reg < 4; ++reg) {
            float v = acc[m4][0][reg] * a0 + acc[m4][1][reg] * a1;
            v += __shfl_xor(v, 1, 16);
            v += __shfl_xor(v, 2, 16);
            v += __shfl_xor(v, 4, 16);
            v += __shfl_xor(v, 8, 16);
            const int node = n0 + m4 * 16 + (lane >> 4) * 4 + reg;
            if ((lane & 15) == reg && node < NNODE)
                scores[node * NHH + w] = v;
        }
    }

    if (STORE) {
        #pragma unroll
        for (int m4 = 0; m4 < 4; ++m4)
            #pragma unroll
            for (int reg = 0; reg < 4; ++reg) {
                const int node = n0 + m4 * 16 + (lane >> 4) * 4 + reg;
                if (node < NNODE) {
                    const __half2 pk = __halves2half2(__float2half_rn(acc[m4][0][reg]),
                                                      __float2half_rn(acc[m4][1][reg]));
                    proj_pk[(size_t)node * 64 + w * 16 + (lane & 15)] = *(const unsigned int*)&pk;
                }
            }
    }
}

// aggregate one target: wave-per-target, lane owns f16x2 pair
// (channel 32w+n, 32w+16+n), w=lane>>4 (= head), n=lane&15.
// int4 slot loads + 8-deep independent gather pipeline.
__device__ __forceinline__
void agg_body(int t, const int* __restrict__ cursor, const int* __restrict__ slots,
              const float* __restrict__ ssrc, const float* __restrict__ strg,
              const unsigned int* __restrict__ src_proj, float* __restrict__ out)
{
    const int lane = threadIdx.x & 63;
    const int h = lane >> 4;
    const float st = strg[t * NHH + h];
    const int cnt = min(cursor[t], DCAP);
    const int* P = slots + t * DCAP;

    float2 acc = make_float2(0.f, 0.f);
    float d = 0.f;
    int j = 0;
    for (; j + 8 <= cnt; j += 8) {
        const int4 A = *(const int4*)(P + j);
        const int4 B = *(const int4*)(P + j + 4);
        const int si[8] = {A.x, A.y, A.z, A.w, B.x, B.y, B.z, B.w};
        float sc[8]; unsigned int wd[8];
        #pragma unroll
        for (int k = 0; k < 8; ++k) {
            sc[k] = ssrc[si[k] * NHH + h];
            wd[k] = src_proj[(size_t)si[k] * 64 + lane];
        }
        #pragma unroll
        for (int k = 0; k < 8; ++k) {
            const float e = __expf(lrelu(sc[k] + st));
            const __half2 hv = *(const __half2*)&wd[k];
            acc.x = fmaf(__low2float(hv),  e, acc.x);
            acc.y = fmaf(__high2float(hv), e, acc.y);
            d += e;
        }
    }
    if (j + 4 <= cnt) {
        const int4 A = *(const int4*)(P + j);
        const int si[4] = {A.x, A.y, A.z, A.w};
        float sc[4]; unsigned int wd[4];
        #pragma unroll
        for (int k = 0; k < 4; ++k) {
            sc[k] = ssrc[si[k] * NHH + h];
            wd[k] = src_proj[(size_t)si[k] * 64 + lane];
        }
        #pragma unroll
        for (int k = 0; k < 4; ++k) {
            const float e = __expf(lrelu(sc[k] + st));
            const __half2 hv = *(const __half2*)&wd[k];
            acc.x = fmaf(__low2float(hv),  e, acc.x);
            acc.y = fmaf(__high2float(hv), e, acc.y);
            d += e;
        }
        j += 4;
    }
    for (; j < cnt; ++j) {
        const int si = P[j];
        const float e = __expf(lrelu(ssrc[si * NHH + h] + st));
        const unsigned int wd = src_proj[(size_t)si * 64 + lane];
        const __half2 hv = *(const __half2*)&wd;
        acc.x = fmaf(__low2float(hv),  e, acc.x);
        acc.y = fmaf(__high2float(hv), e, acc.y);
        d += e;
    }
    const float inv = 1.0f / (d + 1e-16f);
    const int c1 = h * 32 + (lane & 15);
    out[(size_t)t * 128 + c1]      = acc.x * inv;
    out[(size_t)t * 128 + c1 + 16] = acc.y * inv;
}

// ---------------------------------------------------------------------------
// Fused cooperative kernel: phase0 (prep) -> sync -> phase1 (scatter+proj)
// -> sync -> phase2 (aggregate). Grid sized to exact co-residency.
// Phase1 interleave: groups of 24 = 16 scatter + 8 proj (exact 2:1 ratio), so
// every strided block gets a balanced mix; since 24%8==0 and grid%8==0, the
// scatter unit's XCD-range (s&7) == executing block's (blockIdx&7) still holds.
// ---------------------------------------------------------------------------
__global__ __launch_bounds__(256)
void fused_all_kernel(const float* __restrict__ trg, const float* __restrict__ src,
                      const int* __restrict__ ei, const float* __restrict__ Wt,
                      const float* __restrict__ Ws, const float* __restrict__ a_trg,
                      const float* __restrict__ a_src, float* __restrict__ strg,
                      float* __restrict__ ssrc, unsigned int* __restrict__ src_proj,
                      int* __restrict__ cursor, int* __restrict__ slots,
                      __half* __restrict__ wf16, float* __restrict__ out)
{
    __shared__ __align__(16) __half xl[64 * XROW];
    cg::grid_group grid = cg::this_grid();
    const int G = gridDim.x;

    // ---- phase 0: weight conversion + cursor zero (65 units) ----
    for (int u = blockIdx.x; u < 16 + ZBLK; u += G) {
        if (u < 16) prep_w_unit(u, Wt, Ws, wf16);
        else        zero_unit(u - 16, cursor);
    }
    __threadfence();
    grid.sync();

    // ---- phase 1: 196 groups x (16 scatter + 8 proj) ----
    for (int u = blockIdx.x; u < NU1; u += G) {
        const int q = u / 24;
        const int m = u - q * 24;
        if (m < 16) {
            const int s = q * 16 + m;
            if (s < NSCAT) scatter_unit(s, ei, cursor, slots);
        } else {
            const int p = q * 8 + (m - 16);
            if (p < NTILE)
                proj_body<0>(p, trg, wf16, a_trg, nullptr, strg, xl);
            else if (p < 2 * NTILE)
                proj_body<1>(p - NTILE, src, wf16 + 16384, a_src, src_proj, ssrc, xl);
        }
    }
    __threadfence();
    grid.sync();

    // ---- phase 2: aggregate, XCD-aligned target ranges ----
    for (int u = blockIdx.x; u < NAGG; u += G) {
        const int r = u & 7;            // == executing block's XCD (grid%8==0)
        const int i = u >> 3;
        const int o = i * 4 + (threadIdx.x >> 6);
        if (o < TRANGE)
            agg_body(r * TRANGE + o, cursor, slots, ssrc, strg, src_proj, out);
    }
}

// ---------------------------------------------------------------------------
// Fallback 3-kernel path (proven baseline structure, shared unit bodies)
// ---------------------------------------------------------------------------
__global__ __launch_bounds__(256)
void prep_kernel(const float* __restrict__ Wt, const float* __restrict__ Ws,
                 __half* __restrict__ wf16, int* __restrict__ cursor)
{
    const int b = blockIdx.x;
    if (b < 16) prep_w_unit(b, Wt, Ws, wf16);
    else        zero_unit(b - 16, cursor);
}

__global__ __launch_bounds__(256)
void main_fused_kernel(const float* __restrict__ trg, const float* __restrict__ src,
                       const int* __restrict__ ei, const __half* __restrict__ wf16,
                       const float* __restrict__ a_trg, const float* __restrict__ a_src,
                       float* __restrict__ strg, float* __restrict__ ssrc,
                       unsigned int* __restrict__ src_proj,
                       int* __restrict__ cursor, int* __restrict__ slots)
{
    __shared__ __align__(16) __half xl[64 * XROW];
    const int b = blockIdx.x;
    if (b < NSCAT) {
        scatter_unit(b, ei, cursor, slots);
    } else if (b < NSCAT + NTILE) {
        proj_body<0>(b - NSCAT, trg, wf16, a_trg, nullptr, strg, xl);
    } else {
        proj_body<1>(b - NSCAT - NTILE, src, wf16 + 16384, a_src, src_proj, ssrc, xl);
    }
}

__global__ __launch_bounds__(256)
void aggregate_gather_kernel(const int* __restrict__ cursor, const int* __restrict__ slots,
                             const float* __restrict__ ssrc, const float* __restrict__ strg,
                             const unsigned int* __restrict__ src_proj,
                             float* __restrict__ out)
{
    const int t = blockIdx.x * 4 + (threadIdx.x >> 6);
    if (t < NNODE)
        agg_body(t, cursor, slots, ssrc, strg, src_proj, out);
}

// ---------------------------------------------------------------------------
extern "C" void kernel_launch(void* const* d_in, const int* in_sizes, int n_in,
                              void* d_out, int out_size, void* d_ws, size_t ws_size,
                              hipStream_t stream)
{
    const float* trg   = (const float*)d_in[0];
    const float* src   = (const float*)d_in[1];
    const int*   ei    = (const int*)d_in[2];
    const float* Wt    = (const float*)d_in[3];
    const float* Ws    = (const float*)d_in[4];
    const float* a_src = (const float*)d_in[5];
    const float* a_trg = (const float*)d_in[6];
    float* out = (float*)d_out;

    // workspace layout (16B aligned)
    unsigned int* src_proj = (unsigned int*)d_ws;                 // 3,200,000 u32
    float*  ssrc   = (float*)(src_proj + (size_t)NNODE * 64);     //   200,000 f
    float*  strg   = ssrc + NNODE * NHH;                          //   200,000 f
    int*    cursor = (int*)(strg + NNODE * NHH);                  //    50,000 i
    int*    slots  = cursor + NNODE;                              // 3,200,000 i
    __half* wf16   = (__half*)(slots + (size_t)NNODE * DCAP);     //    32,768 h

    static int  g_grid = 0;
    static bool g_coop = true;
    if (g_grid == 0) {
        int nb = 0, ncu = 0, dev = 0;
        hipGetDevice(&dev);
        hipError_t e1 = hipOccupancyMaxActiveBlocksPerMultiprocessor(&nb, fused_all_kernel, 256, 0);
        hipError_t e2 = hipDeviceGetAttribute(&ncu, hipDeviceAttributeMultiprocessorCount, dev);
        if (e1 != hipSuccess || e2 != hipSuccess || nb < 1 || ncu < 1) {
            g_coop = false; g_grid = -1;
        } else {
            g_grid = nb * ncu;          // exact co-residency; multiple of 256 -> %8==0
        }
    }

    if (g_coop) {
        void* args[] = { (void*)&trg, (void*)&src, (void*)&ei, (void*)&Wt, (void*)&Ws,
                         (void*)&a_trg, (void*)&a_src, (void*)&strg, (void*)&ssrc,
                         (void*)&src_proj, (void*)&cursor, (void*)&slots,
                         (void*)&wf16, (void*)&out };
        hipError_t err = hipLaunchCooperativeKernel((const void*)fused_all_kernel,
                                                    dim3(g_grid), dim3(256), args, 0, stream);
        if (err == hipSuccess) return;
        g_coop = false;   // fall through to 3-kernel path from now on
    }

    prep_kernel<<<16 + ZBLK, 256, 0, stream>>>(Wt, Ws, wf16, cursor);
    main_fused_kernel<<<NSCAT + 2 * NTILE, 256, 0, stream>>>(trg, src, ei, wf16,
                                                             a_trg, a_src, strg, ssrc,
                                                             src_proj, cursor, slots);
    aggregate_gather_kernel<<<(NNODE + 3) / 4, 256, 0, stream>>>(cursor, slots, ssrc, strg,
                                                                 src_proj, out);
}

// Round 2
// 179.467 us; speedup vs baseline: 2.4375x; 2.4375x over previous
//
#include <hip/hip_runtime.h>
#include <hip/hip_fp16.h>
#include <math.h>

#define FIN   128
#define NHH   4
#define NNODE 50000
#define NEDGE 800000
#define NTILE 782       // ceil(50000/64)
#define XROW  136       // 128 k + 8 pad (halves)
#define DCAP  64        // per-target slot capacity (deg~Poisson(16); P(>64)~2e-18)
#define SCHUNK 2048     // edges per scatter chunk
#define NCHUNK 391      // ceil(NEDGE/SCHUNK)
#define NSCAT  (NCHUNK * 8)   // 3128 scatter units (chunk x 8 XCD-ranges)
#define TRANGE 6250     // NNODE / 8 targets per XCD-range
#define ZBLK   49       // cursor-zero blocks
#define NU1    4704     // 196 groups x 24 (16 scatter + 8 proj units)
#define NAGG   12504    // 8 ranges x ceil(6250/4) aggregate blocks (multiple of 8)

typedef _Float16 half8   __attribute__((ext_vector_type(8)));
typedef float    floatx4 __attribute__((ext_vector_type(4)));

__device__ __forceinline__ float lrelu(float x) { return x > 0.f ? x : 0.2f * x; }

// ---------------------------------------------------------------------------
// K1: blocks 0..15 convert Wt/Ws -> f16 fragment-tiled (8 blocks each);
//     blocks 16.. zero the per-target cursor (d_ws is poisoned each call).
// B-frag layout: element (w,t,s,lane,j) = W[s*32+(lane>>4)*8+j][w*32+t*16+(lane&15)]
// ---------------------------------------------------------------------------
__global__ __launch_bounds__(256)
void prep_kernel(const float* __restrict__ Wt, const float* __restrict__ Ws,
                 __half* __restrict__ wf16, int* __restrict__ cursor)
{
    const int b = blockIdx.x;
    if (b < 16) {
        const float* W = (b >> 3) ? Ws : Wt;
        __half* o = wf16 + (size_t)(b >> 3) * 16384;
        const int fr = (b & 7) * 256 + threadIdx.x;   // 0..2047
        const int l = fr & 63;
        const int s = (fr >> 6) & 3;
        const int t = (fr >> 8) & 1;
        const int w = fr >> 9;
        const int c  = w * 32 + t * 16 + (l & 15);
        const int k0 = s * 32 + (l >> 4) * 8;
        __half tmp[8];
        #pragma unroll
        for (int j = 0; j < 8; ++j)
            tmp[j] = __float2half_rn(W[(k0 + j) * 128 + c]);
        *(uint4*)(o + (size_t)fr * 8) = *(uint4*)tmp;
    } else {
        const int i = ((b - 16) * 256 + threadIdx.x) * 4;
        if (i < NNODE) {
            if (i + 4 <= NNODE) *(int4*)(cursor + i) = make_int4(0, 0, 0, 0);
            else for (int k = i; k < NNODE; ++k) cursor[k] = 0;
        }
    }
}

// ---------------------------------------------------------------------------
// XCD-partitioned slot scatter; unit s in [0,NSCAT): chunk s>>3, range s&7.
// Executing block satisfies (blockIdx&7)==(s&7) so each cursor/slot line is
// written by ONE XCD's L2 (perf heuristic only; correctness independent).
// ---------------------------------------------------------------------------
__device__ __forceinline__
void scatter_unit(int s, const int* __restrict__ ei, int* __restrict__ cursor,
                  int* __restrict__ slots)
{
    const int base = (s >> 3) * SCHUNK;
    const unsigned lo = (unsigned)((s & 7) * TRANGE);
    #pragma unroll
    for (int k = 0; k < 8; ++k) {
        const int e = base + k * 256 + threadIdx.x;
        if (e < NEDGE) {
            const int ti = ei[NEDGE + e];
            const int si = ei[e];                       // coalesced; filtered below
            if ((unsigned)(ti - lo) < (unsigned)TRANGE) {
                const int p = atomicAdd(cursor + ti, 1);
                if (p < DCAP) slots[ti * DCAP + p] = si;
            }
        }
    }
}

// ---------------------------------------------------------------------------
// MFMA f16 projection body: block = 64 nodes, wave w = head w.
// D layout: channel = (lane&15) + 16*t within head; node = m4*16+(lane>>4)*4+reg.
// STORE: src_proj packed f16x2: dword w*16+n holds channels (32w+n, 32w+16+n).
// ---------------------------------------------------------------------------
template<int STORE>
__device__ __forceinline__
void proj_body(int bb, const float* __restrict__ X, const __half* __restrict__ Wf,
               const float* __restrict__ a, unsigned int* __restrict__ proj_pk,
               float* __restrict__ scores, __half* xl)
{
    const int tid  = threadIdx.x;
    const int lane = tid & 63;
    const int w    = __builtin_amdgcn_readfirstlane(tid >> 6);
    const int n0   = bb * 64;

    {
        const int row = tid >> 2;
        const float4* X4 = (const float4*)X;
        __half2* dst = (__half2*)(xl + row * XROW + (tid & 3) * 32);
        #pragma unroll
        for (int q = 0; q < 8; ++q) {
            float4 v = make_float4(0.f, 0.f, 0.f, 0.f);
            if (n0 + row < NNODE) v = X4[(size_t)(n0 + row) * 32 + (tid & 3) * 8 + q];
            dst[q * 2 + 0] = __halves2half2(__float2half_rn(v.x), __float2half_rn(v.y));
            dst[q * 2 + 1] = __halves2half2(__float2half_rn(v.z), __float2half_rn(v.w));
        }
    }
    __syncthreads();

    half8 bf[2][4];
    {
        const uint4* Bp = (const uint4*)Wf;
        #pragma unroll
        for (int t = 0; t < 2; ++t)
            #pragma unroll
            for (int s = 0; s < 4; ++s) {
                uint4 u = Bp[((size_t)((w * 2 + t) * 4 + s)) * 64 + lane];
                bf[t][s] = *(half8*)&u;
            }
    }

    floatx4 acc[4][2];
    #pragma unroll
    for (int m4 = 0; m4 < 4; ++m4) { acc[m4][0] = (floatx4)0.f; acc[m4][1] = (floatx4)0.f; }

    #pragma unroll
    for (int m4 = 0; m4 < 4; ++m4) {
        #pragma unroll
        for (int s = 0; s < 4; ++s) {
            const half8 af = *(const half8*)(xl + (m4 * 16 + (lane & 15)) * XROW
                                                + s * 32 + (lane >> 4) * 8);
            acc[m4][0] = __builtin_amdgcn_mfma_f32_16x16x32_f16(af, bf[0][s], acc[m4][0], 0, 0, 0);
            acc[m4][1] = __builtin_amdgcn_mfma_f32_16x16x32_f16(af, bf[1][s], acc[m4][1], 0, 0, 0);
        }
    }

    const float a0 = a[w * 32 + (lane & 15)];
    const float a1 = a[w * 32 + 16 + (lane & 15)];
    #pragma unroll
    for (int m4 = 0; m4 < 4; ++m4) {
        #pragma unroll
        for (int reg = 0; reg < 4; ++reg) {
            float v = acc[m4][0][reg] * a0 + acc[m4][1][reg] * a1;
            v += __shfl_xor(v, 1, 16);
            v += __shfl_xor(v, 2, 16);
            v += __shfl_xor(v, 4, 16);
            v += __shfl_xor(v, 8, 16);
            const int node = n0 + m4 * 16 + (lane >> 4) * 4 + reg;
            if ((lane & 15) == reg && node < NNODE)
                scores[node * NHH + w] = v;
        }
    }

    if (STORE) {
        #pragma unroll
        for (int m4 = 0; m4 < 4; ++m4)
            #pragma unroll
            for (int reg = 0; reg < 4; ++reg) {
                const int node = n0 + m4 * 16 + (lane >> 4) * 4 + reg;
                if (node < NNODE) {
                    const __half2 pk = __halves2half2(__float2half_rn(acc[m4][0][reg]),
                                                      __float2half_rn(acc[m4][1][reg]));
                    proj_pk[(size_t)node * 64 + w * 16 + (lane & 15)] = *(const unsigned int*)&pk;
                }
            }
    }
}

// ---------------------------------------------------------------------------
// K2: interleaved scatter+proj. Block b -> group q=b/24, slot m=b%24:
//   m<16: scatter unit s=q*16+m  (b&7 == m&7 == s&7, since 24q=16q=0 mod 8)
//   else: proj unit p=q*8+(m-16) (trg if p<NTILE, src+store otherwise)
// The 2:1 ratio matches NSCAT:2*NTILE exactly (3128:1564), so scatter
// (atomic/latency-bound) and proj (MFMA-bound) overlap across the machine
// instead of running as back-to-back phases.
// ---------------------------------------------------------------------------
__global__ __launch_bounds__(256)
void main_fused_kernel(const float* __restrict__ trg, const float* __restrict__ src,
                       const int* __restrict__ ei, const __half* __restrict__ wf16,
                       const float* __restrict__ a_trg, const float* __restrict__ a_src,
                       float* __restrict__ strg, float* __restrict__ ssrc,
                       unsigned int* __restrict__ src_proj,
                       int* __restrict__ cursor, int* __restrict__ slots)
{
    __shared__ __align__(16) __half xl[64 * XROW];
    const int b = blockIdx.x;
    const int q = b / 24;
    const int m = b - q * 24;
    if (m < 16) {
        const int s = q * 16 + m;
        if (s < NSCAT) scatter_unit(s, ei, cursor, slots);
    } else {
        const int p = q * 8 + (m - 16);
        if (p < NTILE)
            proj_body<0>(p, trg, wf16, a_trg, nullptr, strg, xl);
        else if (p < 2 * NTILE)
            proj_body<1>(p - NTILE, src, wf16 + 16384, a_src, src_proj, ssrc, xl);
    }
}

// ---------------------------------------------------------------------------
// K3: aggregate (gather): one wave per target; lane owns the f16x2 pair
// (channel 32w+n, 32w+16+n), w=lane>>4 (= head), n=lane&15.
// Block b handles XCD-range r=b&7 (same L2 that wrote those cursor/slot
// lines), targets r*TRANGE + (b>>3)*4 + wave.
// int4 slot loads + 8-deep independent gather pipeline (all indices static).
// ---------------------------------------------------------------------------
__global__ __launch_bounds__(256)
void aggregate_gather_kernel(const int* __restrict__ cursor, const int* __restrict__ slots,
                             const float* __restrict__ ssrc, const float* __restrict__ strg,
                             const unsigned int* __restrict__ src_proj,
                             float* __restrict__ out)
{
    const int lane = threadIdx.x & 63;
    const int wv   = threadIdx.x >> 6;
    const int r = blockIdx.x & 7;
    const int o = (blockIdx.x >> 3) * 4 + wv;
    if (o >= TRANGE) return;
    const int t = r * TRANGE + o;

    const int h = lane >> 4;
    const float st = strg[t * NHH + h];
    const int cnt = min(cursor[t], DCAP);
    const int* P = slots + t * DCAP;

    float2 acc = make_float2(0.f, 0.f);
    float d = 0.f;
    int j = 0;
    for (; j + 8 <= cnt; j += 8) {
        const int4 A = *(const int4*)(P + j);
        const int4 B = *(const int4*)(P + j + 4);
        const int si[8] = {A.x, A.y, A.z, A.w, B.x, B.y, B.z, B.w};
        float sc[8]; unsigned int wd[8];
        #pragma unroll
        for (int k = 0; k < 8; ++k) {
            sc[k] = ssrc[si[k] * NHH + h];
            wd[k] = src_proj[(size_t)si[k] * 64 + lane];
        }
        #pragma unroll
        for (int k = 0; k < 8; ++k) {
            const float e = __expf(lrelu(sc[k] + st));
            const __half2 hv = *(const __half2*)&wd[k];
            acc.x = fmaf(__low2float(hv),  e, acc.x);
            acc.y = fmaf(__high2float(hv), e, acc.y);
            d += e;
        }
    }
    if (j + 4 <= cnt) {
        const int4 A = *(const int4*)(P + j);
        const int si[4] = {A.x, A.y, A.z, A.w};
        float sc[4]; unsigned int wd[4];
        #pragma unroll
        for (int k = 0; k < 4; ++k) {
            sc[k] = ssrc[si[k] * NHH + h];
            wd[k] = src_proj[(size_t)si[k] * 64 + lane];
        }
        #pragma unroll
        for (int k = 0; k < 4; ++k) {
            const float e = __expf(lrelu(sc[k] + st));
            const __half2 hv = *(const __half2*)&wd[k];
            acc.x = fmaf(__low2float(hv),  e, acc.x);
            acc.y = fmaf(__high2float(hv), e, acc.y);
            d += e;
        }
        j += 4;
    }
    for (; j < cnt; ++j) {
        const int si = P[j];
        const float e = __expf(lrelu(ssrc[si * NHH + h] + st));
        const unsigned int wd = src_proj[(size_t)si * 64 + lane];
        const __half2 hv = *(const __half2*)&wd;
        acc.x = fmaf(__low2float(hv),  e, acc.x);
        acc.y = fmaf(__high2float(hv), e, acc.y);
        d += e;
    }
    const float inv = 1.0f / (d + 1e-16f);
    const int c1 = h * 32 + (lane & 15);
    out[(size_t)t * 128 + c1]      = acc.x * inv;
    out[(size_t)t * 128 + c1 + 16] = acc.y * inv;
}

// ---------------------------------------------------------------------------
extern "C" void kernel_launch(void* const* d_in, const int* in_sizes, int n_in,
                              void* d_out, int out_size, void* d_ws, size_t ws_size,
                              hipStream_t stream)
{
    const float* trg   = (const float*)d_in[0];
    const float* src   = (const float*)d_in[1];
    const int*   ei    = (const int*)d_in[2];
    const float* Wt    = (const float*)d_in[3];
    const float* Ws    = (const float*)d_in[4];
    const float* a_src = (const float*)d_in[5];
    const float* a_trg = (const float*)d_in[6];
    float* out = (float*)d_out;

    // workspace layout (16B aligned)
    unsigned int* src_proj = (unsigned int*)d_ws;                 // 3,200,000 u32
    float*  ssrc   = (float*)(src_proj + (size_t)NNODE * 64);     //   200,000 f
    float*  strg   = ssrc + NNODE * NHH;                          //   200,000 f
    int*    cursor = (int*)(strg + NNODE * NHH);                  //    50,000 i
    int*    slots  = cursor + NNODE;                              // 3,200,000 i
    __half* wf16   = (__half*)(slots + (size_t)NNODE * DCAP);     //    32,768 h

    prep_kernel<<<16 + ZBLK, 256, 0, stream>>>(Wt, Ws, wf16, cursor);
    main_fused_kernel<<<NU1, 256, 0, stream>>>(trg, src, ei, wf16,
                                               a_trg, a_src, strg, ssrc,
                                               src_proj, cursor, slots);
    aggregate_gather_kernel<<<NAGG, 256, 0, stream>>>(cursor, slots, ssrc, strg,
                                                      src_proj, out);
}

// Round 3
// 176.570 us; speedup vs baseline: 2.4775x; 1.0164x over previous
//
#include <hip/hip_runtime.h>
#include <hip/hip_fp16.h>
#include <math.h>

#define FIN   128
#define NHH   4
#define NNODE 50000
#define NEDGE 800000
#define NTILE 782       // ceil(50000/64)
#define XROW  136       // 128 k + 8 pad (halves)
#define DCAP  64        // per-target slot capacity (deg~Poisson(16); P(>64)~2e-18)
#define SCHUNK 2048     // edges per scatter chunk
#define NCHUNK 391      // ceil(NEDGE/SCHUNK)
#define NSCAT  (NCHUNK * 8)   // 3128 scatter units (chunk x 8 XCD-ranges)
#define TRANGE 6250     // NNODE / 8 targets per XCD-range
#define ZBLK   49       // cursor-zero blocks
#define NU1    4704     // 196 groups x 24 (16 scatter + 8 proj units)
#define NAGG   12504    // 8 ranges x ceil(6250/4) aggregate blocks (multiple of 8)

typedef _Float16 half8   __attribute__((ext_vector_type(8)));
typedef float    floatx4 __attribute__((ext_vector_type(4)));

__device__ __forceinline__ float lrelu(float x) { return x > 0.f ? x : 0.2f * x; }

// ---------------------------------------------------------------------------
// K1: blocks 0..15 convert Wt/Ws -> f16 fragment-tiled (8 blocks each);
//     blocks 16.. zero the per-target cursor (d_ws is poisoned each call).
// B-frag layout: element (w,t,s,lane,j) = W[s*32+(lane>>4)*8+j][w*32+t*16+(lane&15)]
// ---------------------------------------------------------------------------
__global__ __launch_bounds__(256)
void prep_kernel(const float* __restrict__ Wt, const float* __restrict__ Ws,
                 __half* __restrict__ wf16, int* __restrict__ cursor)
{
    const int b = blockIdx.x;
    if (b < 16) {
        const float* W = (b >> 3) ? Ws : Wt;
        __half* o = wf16 + (size_t)(b >> 3) * 16384;
        const int fr = (b & 7) * 256 + threadIdx.x;   // 0..2047
        const int l = fr & 63;
        const int s = (fr >> 6) & 3;
        const int t = (fr >> 8) & 1;
        const int w = fr >> 9;
        const int c  = w * 32 + t * 16 + (l & 15);
        const int k0 = s * 32 + (l >> 4) * 8;
        __half tmp[8];
        #pragma unroll
        for (int j = 0; j < 8; ++j)
            tmp[j] = __float2half_rn(W[(k0 + j) * 128 + c]);
        *(uint4*)(o + (size_t)fr * 8) = *(uint4*)tmp;
    } else {
        const int i = ((b - 16) * 256 + threadIdx.x) * 4;
        if (i < NNODE) {
            if (i + 4 <= NNODE) *(int4*)(cursor + i) = make_int4(0, 0, 0, 0);
            else for (int k = i; k < NNODE; ++k) cursor[k] = 0;
        }
    }
}

// ---------------------------------------------------------------------------
// XCD-partitioned slot scatter; unit s in [0,NSCAT): chunk s>>3, range s&7.
// Executing block satisfies (blockIdx&7)==(s&7) so each cursor/slot line is
// written by ONE XCD's L2 (perf heuristic only; correctness independent).
// ---------------------------------------------------------------------------
__device__ __forceinline__
void scatter_unit(int s, const int* __restrict__ ei, int* __restrict__ cursor,
                  int* __restrict__ slots)
{
    const int base = (s >> 3) * SCHUNK;
    const unsigned lo = (unsigned)((s & 7) * TRANGE);
    #pragma unroll
    for (int k = 0; k < 8; ++k) {
        const int e = base + k * 256 + threadIdx.x;
        if (e < NEDGE) {
            const int ti = ei[NEDGE + e];
            const int si = ei[e];                       // coalesced; filtered below
            if ((unsigned)(ti - lo) < (unsigned)TRANGE) {
                const int p = atomicAdd(cursor + ti, 1);
                if (p < DCAP) slots[ti * DCAP + p] = si;
            }
        }
    }
}

// ---------------------------------------------------------------------------
// MFMA f16 projection body: block = 64 nodes, wave w = head w.
// D layout: channel = (lane&15) + 16*t within head; node = m4*16+(lane>>4)*4+reg.
// STORE: src_proj packed f16x2: dword w*16+n holds channels (32w+n, 32w+16+n).
// ---------------------------------------------------------------------------
template<int STORE>
__device__ __forceinline__
void proj_body(int bb, const float* __restrict__ X, const __half* __restrict__ Wf,
               const float* __restrict__ a, unsigned int* __restrict__ proj_pk,
               float* __restrict__ scores, __half* xl)
{
    const int tid  = threadIdx.x;
    const int lane = tid & 63;
    const int w    = __builtin_amdgcn_readfirstlane(tid >> 6);
    const int n0   = bb * 64;

    {
        const int row = tid >> 2;
        const float4* X4 = (const float4*)X;
        __half2* dst = (__half2*)(xl + row * XROW + (tid & 3) * 32);
        #pragma unroll
        for (int q = 0; q < 8; ++q) {
            float4 v = make_float4(0.f, 0.f, 0.f, 0.f);
            if (n0 + row < NNODE) v = X4[(size_t)(n0 + row) * 32 + (tid & 3) * 8 + q];
            dst[q * 2 + 0] = __halves2half2(__float2half_rn(v.x), __float2half_rn(v.y));
            dst[q * 2 + 1] = __halves2half2(__float2half_rn(v.z), __float2half_rn(v.w));
        }
    }
    __syncthreads();

    half8 bf[2][4];
    {
        const uint4* Bp = (const uint4*)Wf;
        #pragma unroll
        for (int t = 0; t < 2; ++t)
            #pragma unroll
            for (int s = 0; s < 4; ++s) {
                uint4 u = Bp[((size_t)((w * 2 + t) * 4 + s)) * 64 + lane];
                bf[t][s] = *(half8*)&u;
            }
    }

    floatx4 acc[4][2];
    #pragma unroll
    for (int m4 = 0; m4 < 4; ++m4) { acc[m4][0] = (floatx4)0.f; acc[m4][1] = (floatx4)0.f; }

    #pragma unroll
    for (int m4 = 0; m4 < 4; ++m4) {
        #pragma unroll
        for (int s = 0; s < 4; ++s) {
            const half8 af = *(const half8*)(xl + (m4 * 16 + (lane & 15)) * XROW
                                                + s * 32 + (lane >> 4) * 8);
            acc[m4][0] = __builtin_amdgcn_mfma_f32_16x16x32_f16(af, bf[0][s], acc[m4][0], 0, 0, 0);
            acc[m4][1] = __builtin_amdgcn_mfma_f32_16x16x32_f16(af, bf[1][s], acc[m4][1], 0, 0, 0);
        }
    }

    const float a0 = a[w * 32 + (lane & 15)];
    const float a1 = a[w * 32 + 16 + (lane & 15)];
    #pragma unroll
    for (int m4 = 0; m4 < 4; ++m4) {
        #pragma unroll
        for (int reg = 0; reg < 4; ++reg) {
            float v = acc[m4][0][reg] * a0 + acc[m4][1][reg] * a1;
            v += __shfl_xor(v, 1, 16);
            v += __shfl_xor(v, 2, 16);
            v += __shfl_xor(v, 4, 16);
            v += __shfl_xor(v, 8, 16);
            const int node = n0 + m4 * 16 + (lane >> 4) * 4 + reg;
            if ((lane & 15) == reg && node < NNODE)
                scores[node * NHH + w] = v;
        }
    }

    if (STORE) {
        #pragma unroll
        for (int m4 = 0; m4 < 4; ++m4)
            #pragma unroll
            for (int reg = 0; reg < 4; ++reg) {
                const int node = n0 + m4 * 16 + (lane >> 4) * 4 + reg;
                if (node < NNODE) {
                    const __half2 pk = __halves2half2(__float2half_rn(acc[m4][0][reg]),
                                                      __float2half_rn(acc[m4][1][reg]));
                    proj_pk[(size_t)node * 64 + w * 16 + (lane & 15)] = *(const unsigned int*)&pk;
                }
            }
    }
}

// ---------------------------------------------------------------------------
// K2: interleaved scatter+proj. Block b -> group q=b/24, slot m=b%24:
//   m<16: scatter unit s=q*16+m  (b&7 == m&7 == s&7, since 24q=16q=0 mod 8)
//   else: proj unit p=q*8+(m-16) (trg if p<NTILE, src+store otherwise)
// ---------------------------------------------------------------------------
__global__ __launch_bounds__(256)
void main_fused_kernel(const float* __restrict__ trg, const float* __restrict__ src,
                       const int* __restrict__ ei, const __half* __restrict__ wf16,
                       const float* __restrict__ a_trg, const float* __restrict__ a_src,
                       float* __restrict__ strg, float* __restrict__ ssrc,
                       unsigned int* __restrict__ src_proj,
                       int* __restrict__ cursor, int* __restrict__ slots)
{
    __shared__ __align__(16) __half xl[64 * XROW];
    const int b = blockIdx.x;
    const int q = b / 24;
    const int m = b - q * 24;
    if (m < 16) {
        const int s = q * 16 + m;
        if (s < NSCAT) scatter_unit(s, ei, cursor, slots);
    } else {
        const int p = q * 8 + (m - 16);
        if (p < NTILE)
            proj_body<0>(p, trg, wf16, a_trg, nullptr, strg, xl);
        else if (p < 2 * NTILE)
            proj_body<1>(p - NTILE, src, wf16 + 16384, a_src, src_proj, ssrc, xl);
    }
}

// ---------------------------------------------------------------------------
// K3: aggregate (gather), half-wave edge parallelism.
// Wave = one target. Lanes split into two 32-lane halves; each half covers
// ALL 64 src_proj dwords (uint2 = dwords {2*li, 2*li+1} per lane) and owns
// alternating edges (half_id = edge parity). 16 edges in flight per round;
// fully predicated (no serial tail): out-of-range slot indices sanitized to
// 0 and their exp weight zeroed, so deg 1..64 all run 1..4 pipelined rounds.
// Halves combined at the end via shfl_xor(32).
// dword dw=w*16+n holds channels (32w+n, 32w+16+n); lane li owns dw=2li,2li+1
// -> head h = li>>3, cols w*32 + {n0,n0+1} and +16 (n0 = (2li)&15, even).
// ---------------------------------------------------------------------------
__global__ __launch_bounds__(256)
void aggregate_gather_kernel(const int* __restrict__ cursor, const int* __restrict__ slots,
                             const float* __restrict__ ssrc, const float* __restrict__ strg,
                             const unsigned int* __restrict__ src_proj,
                             float* __restrict__ out)
{
    const int lane = threadIdx.x & 63;
    const int wv   = threadIdx.x >> 6;
    const int r = blockIdx.x & 7;
    const int o = (blockIdx.x >> 3) * 4 + wv;
    if (o >= TRANGE) return;
    const int t = r * TRANGE + o;

    const int half_id = lane >> 5;
    const int li      = lane & 31;
    const int h       = li >> 3;                // head of dwords 2li,2li+1
    const float st = strg[t * NHH + h];
    const int cnt = min(cursor[t], DCAP);
    const int* P = slots + t * DCAP;
    const uint2* SP = (const uint2*)src_proj;   // 32 uint2 per node row

    float4 acc = make_float4(0.f, 0.f, 0.f, 0.f);
    float d = 0.f;
    for (int j = 0; j < cnt; j += 16) {
        // always in-bounds: j <= 48, reads P[j..j+15] within DCAP=64
        const int4 A0 = *(const int4*)(P + j);
        const int4 A1 = *(const int4*)(P + j + 4);
        const int4 A2 = *(const int4*)(P + j + 8);
        const int4 A3 = *(const int4*)(P + j + 12);
        int   si[8];
        bool  vl[8];
        si[0] = half_id ? A0.y : A0.x;  si[1] = half_id ? A0.w : A0.z;
        si[2] = half_id ? A1.y : A1.x;  si[3] = half_id ? A1.w : A1.z;
        si[4] = half_id ? A2.y : A2.x;  si[5] = half_id ? A2.w : A2.z;
        si[6] = half_id ? A3.y : A3.x;  si[7] = half_id ? A3.w : A3.z;
        #pragma unroll
        for (int k = 0; k < 8; ++k) {
            vl[k] = (j + 2 * k + half_id) < cnt;
            si[k] = vl[k] ? si[k] : 0;          // sanitize poison beyond cnt
        }
        float sc[8]; uint2 wd[8];
        #pragma unroll
        for (int k = 0; k < 8; ++k) {
            sc[k] = ssrc[si[k] * NHH + h];
            wd[k] = SP[(size_t)si[k] * 32 + li];
        }
        #pragma unroll
        for (int k = 0; k < 8; ++k) {
            float e = __expf(lrelu(sc[k] + st));
            e = vl[k] ? e : 0.f;
            const __half2 h0 = *(const __half2*)&wd[k].x;
            const __half2 h1 = *(const __half2*)&wd[k].y;
            acc.x = fmaf(__low2float(h0),  e, acc.x);
            acc.y = fmaf(__high2float(h0), e, acc.y);
            acc.z = fmaf(__low2float(h1),  e, acc.z);
            acc.w = fmaf(__high2float(h1), e, acc.w);
            d += e;
        }
    }
    // combine halves (disjoint edge subsets, same channel coverage)
    acc.x += __shfl_xor(acc.x, 32);
    acc.y += __shfl_xor(acc.y, 32);
    acc.z += __shfl_xor(acc.z, 32);
    acc.w += __shfl_xor(acc.w, 32);
    d     += __shfl_xor(d, 32);

    const float inv = 1.0f / (d + 1e-16f);
    const int w  = li >> 3;
    const int nn = (2 * li) & 15;               // even
    const size_t ob = (size_t)t * 128 + w * 32 + nn;
    *(float2*)(out + ob)      = make_float2(acc.x * inv, acc.z * inv);
    *(float2*)(out + ob + 16) = make_float2(acc.y * inv, acc.w * inv);
}

// ---------------------------------------------------------------------------
extern "C" void kernel_launch(void* const* d_in, const int* in_sizes, int n_in,
                              void* d_out, int out_size, void* d_ws, size_t ws_size,
                              hipStream_t stream)
{
    const float* trg   = (const float*)d_in[0];
    const float* src   = (const float*)d_in[1];
    const int*   ei    = (const int*)d_in[2];
    const float* Wt    = (const float*)d_in[3];
    const float* Ws    = (const float*)d_in[4];
    const float* a_src = (const float*)d_in[5];
    const float* a_trg = (const float*)d_in[6];
    float* out = (float*)d_out;

    // workspace layout (16B aligned)
    unsigned int* src_proj = (unsigned int*)d_ws;                 // 3,200,000 u32
    float*  ssrc   = (float*)(src_proj + (size_t)NNODE * 64);     //   200,000 f
    float*  strg   = ssrc + NNODE * NHH;                          //   200,000 f
    int*    cursor = (int*)(strg + NNODE * NHH);                  //    50,000 i
    int*    slots  = cursor + NNODE;                              // 3,200,000 i
    __half* wf16   = (__half*)(slots + (size_t)NNODE * DCAP);     //    32,768 h

    prep_kernel<<<16 + ZBLK, 256, 0, stream>>>(Wt, Ws, wf16, cursor);
    main_fused_kernel<<<NU1, 256, 0, stream>>>(trg, src, ei, wf16,
                                               a_trg, a_src, strg, ssrc,
                                               src_proj, cursor, slots);
    aggregate_gather_kernel<<<NAGG, 256, 0, stream>>>(cursor, slots, ssrc, strg,
                                                      src_proj, out);
}